// Round 16
// baseline (512.618 us; speedup 1.0000x reference)
//
#include <hip/hip_runtime.h>
#include <hip/hip_bf16.h>
#include <math.h>

#define B_SZ   16384
#define IN_SZ  512
#define CH_SZ  1024
#define ED_SZ  4096
#define NC_SZ  8
#define NE_SZ  512
#define D_SZ   512

typedef short short8 __attribute__((ext_vector_type(8)));
typedef float f32x4 __attribute__((ext_vector_type(4)));

#define SWZ(r) ((((r)&3)^(((r)>>2)&3)))

__device__ __forceinline__ ushort f2bf(float f) {
  union { float f; unsigned u; } v; v.f = f;
  unsigned u = v.u;
  return (ushort)((u + 0x7fffu + ((u >> 16) & 1u)) >> 16);  // RNE
}
__device__ __forceinline__ float bf2f(ushort h) {
  union { unsigned u; float f; } v; v.u = ((unsigned)h) << 16; return v.f;
}

__device__ __forceinline__ void gload_lds16(const void* g, void* l) {
  __builtin_amdgcn_global_load_lds(
      (const __attribute__((address_space(1))) void*)g,
      (__attribute__((address_space(3))) void*)l, 16, 0, 0);
}

#define WAITV(N) asm volatile("s_waitcnt vmcnt(" #N ")" ::: "memory")
#define WAITL()  asm volatile("s_waitcnt lgkmcnt(0)" ::: "memory")
#define BAR()    asm volatile("s_barrier" ::: "memory")
#define SP1()    __builtin_amdgcn_s_setprio(1)
#define SP0()    __builtin_amdgcn_s_setprio(0)

// ========== k_prep: coalesced converts + inits (R15, unchanged) ===========
#define P_S0 2097152L
#define P_S1 131072L
#define P_S2 131072L
#define P_S3 1048576L
#define P_S4 16384L
#define P_S5 4096L
#define P_S6 131072L
#define P_S7 4097L
#define P_TOTAL (P_S0+P_S1+P_S2+P_S3+P_S4+P_S5+P_S6+P_S7)

__device__ __forceinline__ void cvt4(const float* __restrict__ s,
                                     ushort* __restrict__ d, long i4) {
  float4 v = ((const float4*)s)[i4];
  ushort4 o; o.x=f2bf(v.x); o.y=f2bf(v.y); o.z=f2bf(v.z); o.w=f2bf(v.w);
  ((ushort4*)d)[i4] = o;
}

__global__ __launch_bounds__(256) void k_prep(
    const float* __restrict__ x, const float* __restrict__ W_f,
    const float* __restrict__ W_x1, const float* __restrict__ Wq,
    const float* __restrict__ W_x2,
    ushort* __restrict__ xb, ushort* __restrict__ wcat,
    ushort* __restrict__ wqb, ushort* __restrict__ wx2b,
    float* __restrict__ esq, unsigned long long* __restrict__ amin,
    int* __restrict__ counts, float* __restrict__ dacc)
{
  long id = (long)blockIdx.x*256 + threadIdx.x;
  if (id < P_S0) { cvt4(x, xb, id); return; }            id -= P_S0;
  if (id < P_S1) { cvt4(W_f, wcat, id); return; }        id -= P_S1;
  if (id < P_S2) { cvt4(W_x1, wcat + (size_t)CH_SZ*IN_SZ, id); return; } id -= P_S2;
  if (id < P_S3) { cvt4(Wq, wqb, id); return; }          id -= P_S3;
  if (id < P_S4) {                                        // wx2 pad [64][1024]
    long i = id*4; int row = (int)(i >> 10), col = (int)(i & 1023);
    ushort4 o;
    if (row < 63) {
      float4 v = *(const float4*)(W_x2 + (size_t)row*1024 + col);
      o.x=f2bf(v.x); o.y=f2bf(v.y); o.z=f2bf(v.z); o.w=f2bf(v.w);
    } else { o.x=o.y=o.z=o.w=0; }
    *(ushort4*)(wx2b + i) = o;
    return;
  }                                                       id -= P_S4;
  if (id < P_S5) { esq[id] = 0.f; return; }               id -= P_S5;
  if (id < P_S6) { amin[id] = ~0ull; return; }            id -= P_S6;
  if (id < 4096) { counts[id] = 0; return; }
  if (id == 4096) { dacc[0] = 0.f; }
}

// coalesced LDS-transpose embT + esq (proven)
__global__ void k_embT(const float* __restrict__ embed,
                       ushort* __restrict__ embT, float* __restrict__ e_sq) {
  __shared__ float t[32][33];
  int c = blockIdx.x, d0 = blockIdx.y*32, n0 = blockIdx.z*32;
  const float* src = embed + ((size_t)c*D_SZ + d0)*NE_SZ + n0;
  for (int dy = threadIdx.y; dy < 32; dy += 8)
    t[dy][threadIdx.x] = src[(size_t)dy*NE_SZ + threadIdx.x];
  __syncthreads();
  ushort* dst = embT + ((size_t)c*NE_SZ + n0)*D_SZ + d0;
  for (int ny = threadIdx.y; ny < 32; ny += 8)
    dst[(size_t)ny*D_SZ + threadIdx.x] = f2bf(t[threadIdx.x][ny]);
  if (threadIdx.y == 0) {
    float s = 0.f;
    #pragma unroll
    for (int dd = 0; dd < 32; ++dd) { float v = t[dd][threadIdx.x]; s += v*v; }
    atomicAdd(&e_sq[c*NE_SZ + n0 + threadIdx.x], s);
  }
}

// ===================== fused z + dist kernel (R15, unchanged) =============
__global__ __launch_bounds__(512, 2) void k_zdist(
    const ushort* __restrict__ preB, const ushort* __restrict__ WqB,
    const float* __restrict__ bq, const ushort* __restrict__ embT,
    const float* __restrict__ esq, float* __restrict__ zzG,
    unsigned long long* __restrict__ amin)
{
  __shared__ ushort smem[81920];                 // 160 KB
  const int tid = threadIdx.x;
  const int lane = tid & 63;
  const int w = tid >> 6;
  const int wm = w >> 2, wn = w & 3;             // 2M x 4N waves
  const int g = lane >> 4, c0 = lane & 15;
  const int bid = blockIdx.x;
  const int c = bid >> 7;                        // codebook (XCD remap)
  const int mBase = (bid & 127) * 128;

  const int af0 = tid, af1 = tid + 512;
  const int ar0 = af0 >> 3, ar1 = af1 >> 3;
  const ushort* aSrc0 = preB + (size_t)(mBase + ar0)*CH_SZ + (((af0 & 7) ^ (ar0 & 7)) * 8);
  const ushort* aSrc1 = preB + (size_t)(mBase + ar1)*CH_SZ + (((af1 & 7) ^ (ar1 & 7)) * 8);
  const ushort* bSrcW[8];
  #pragma unroll
  for (int j = 0; j < 8; ++j) {
    int q = tid + j*512, br = q >> 3, bs = ((q & 7) ^ (br & 7)) * 8;
    bSrcW[j] = WqB + (size_t)(c*512 + br)*CH_SZ + bs;
  }

  f32x4 acc[4][8];
  #pragma unroll
  for (int m=0;m<4;++m)
    #pragma unroll
    for (int n=0;n<8;++n) acc[m][n] = (f32x4){0.f,0.f,0.f,0.f};

  {
    auto issue = [&](int t) {
      int kt = t * 64;
      ushort* ab = smem + (t & 1)*40960;
      ushort* bb = ab + 8192;
      gload_lds16(aSrc0 + kt, ab + af0*8);
      gload_lds16(aSrc1 + kt, ab + af1*8);
      #pragma unroll
      for (int j=0;j<8;++j) gload_lds16(bSrcW[j] + kt, bb + (tid + j*512)*8);
    };
    issue(0);
    for (int t = 0; t < 16; ++t) {
      WAITV(0); BAR();
      if (t + 1 < 16) issue(t + 1);
      const ushort* ab = smem + (t & 1)*40960;
      const ushort* bb = ab + 8192;
      #pragma unroll
      for (int ks = 0; ks < 2; ++ks) {
        short8 af[4], bf2[8];
        #pragma unroll
        for (int m=0;m<4;++m) {
          int ar = wm*64 + m*16 + c0;
          af[m] = *(const short8*)(ab + ar*64 + (((ks*4+g) ^ (ar & 7)) * 8));
        }
        #pragma unroll
        for (int n=0;n<8;++n) {
          int br = wn*128 + n*16 + c0;
          bf2[n] = *(const short8*)(bb + br*64 + (((ks*4+g) ^ (br & 7)) * 8));
        }
        SP1();
        #pragma unroll
        for (int m=0;m<4;++m)
          #pragma unroll
          for (int n=0;n<8;++n)
            acc[m][n] = __builtin_amdgcn_mfma_f32_16x16x32_bf16(af[m], bf2[n], acc[m][n], 0, 0, 0);
        SP0();
      }
    }
    BAR();
  }

  // phase 2: acc -> Z bf16 in LDS (swizzled) + row norms
  #pragma unroll
  for (int m=0;m<4;++m) {
    float sq[4] = {0.f,0.f,0.f,0.f};
    #pragma unroll
    for (int n=0;n<8;++n) {
      int col = wn*128 + n*16 + c0;
      float bb = bq[c*512 + col];
      #pragma unroll
      for (int r=0;r<4;++r) {
        int row = wm*64 + m*16 + g*4 + r;
        float v = acc[m][n][r] + bb;
        ushort hb = f2bf(v);
        int byte = row*1024 + ((col*2) ^ ((row&7)<<4));
        smem[byte>>1] = hb;
        float vb = bf2f(hb);
        sq[r] += vb*vb;
      }
    }
    #pragma unroll
    for (int r=0;r<4;++r) {
      float s = sq[r];
      s += __shfl_xor(s,1); s += __shfl_xor(s,2);
      s += __shfl_xor(s,4); s += __shfl_xor(s,8);
      if (c0 == 0) {
        int row = wm*64 + m*16 + g*4 + r;
        zzG[(size_t)(mBase + row)*NC_SZ + c] = s;
      }
    }
  }
  WAITL();
  BAR();

  // phase 3: dist GEMM from Z-LDS, staged embT ping-pong
  float rv[4][4]; int ri[4][4];
  #pragma unroll
  for (int m=0;m<4;++m)
    #pragma unroll
    for (int r=0;r<4;++r) { rv[m][r] = 3.0e38f; ri[m][r] = 0; }

  for (int h = 0; h < 2; ++h) {
    const ushort* eS0;
    const ushort* eS1;
    {
      int f0 = tid, f1 = tid + 512;
      int er0 = f0 >> 2, es0 = ((f0 & 3) ^ SWZ(er0)) * 8;
      int er1 = f1 >> 2, es1 = ((f1 & 3) ^ SWZ(er1)) * 8;
      eS0 = embT + (size_t)(c*512 + h*256 + er0)*512 + es0;
      eS1 = embT + (size_t)(c*512 + h*256 + er1)*512 + es1;
    }
    f32x4 acc2[4][4];
    #pragma unroll
    for (int m=0;m<4;++m)
      #pragma unroll
      for (int n=0;n<4;++n) acc2[m][n] = (f32x4){0.f,0.f,0.f,0.f};

    auto issue_e = [&](int s) {
      int kt = s * 32;
      ushort* eb = smem + 65536 + (s & 1)*8192;
      gload_lds16(eS0 + kt, eb + tid*8);
      gload_lds16(eS1 + kt, eb + (tid + 512)*8);
    };
    issue_e(0); issue_e(1);
    for (int s = 0; s < 16; ++s) {
      if (s < 15) { WAITV(2); } else { WAITV(0); }
      BAR();
      const ushort* eb = smem + 65536 + (s & 1)*8192;
      short8 af[4], bf2[4];
      #pragma unroll
      for (int m=0;m<4;++m) {
        int ar = wm*64 + m*16 + c0;
        af[m] = *(const short8*)(smem + ((ar*1024 + ((s*64 + g*16) ^ ((ar&7)<<4)))>>1));
      }
      #pragma unroll
      for (int n=0;n<4;++n) {
        int rbr = wn*64 + n*16 + c0;
        bf2[n] = *(const short8*)(eb + ((rbr*64 + ((g ^ SWZ(rbr))<<4))>>1));
      }
      SP1();
      #pragma unroll
      for (int m=0;m<4;++m)
        #pragma unroll
        for (int n=0;n<4;++n)
          acc2[m][n] = __builtin_amdgcn_mfma_f32_16x16x32_bf16(af[m], bf2[n], acc2[m][n], 0, 0, 0);
      SP0();
      BAR();
      if (s + 2 < 16) issue_e(s + 2);
    }
    #pragma unroll
    for (int m=0;m<4;++m)
      #pragma unroll
      for (int n=0;n<4;++n) {
        int ne = h*256 + wn*64 + n*16 + c0;
        float ev = esq[c*512 + ne];
        #pragma unroll
        for (int r=0;r<4;++r) {
          float v = ev - 2.0f*acc2[m][n][r];
          if (v < rv[m][r]) { rv[m][r] = v; ri[m][r] = ne; }
        }
      }
  }

  #pragma unroll
  for (int m=0;m<4;++m)
    #pragma unroll
    for (int r=0;r<4;++r) {
      float bv = rv[m][r]; int bi = ri[m][r];
      #pragma unroll
      for (int off=1; off<16; off<<=1) {
        float ov = __shfl_xor(bv, off);
        int   oi = __shfl_xor(bi, off);
        if (ov < bv || (ov == bv && oi < bi)) { bv = ov; bi = oi; }
      }
      if (c0 == 0) {
        unsigned u; { union {float f; unsigned uu;} cv; cv.f = bv; u = cv.uu; }
        unsigned k = (u & 0x80000000u) ? ~u : (u | 0x80000000u);
        unsigned long long key = (((unsigned long long)k) << 32) | (unsigned)bi;
        int row = wm*64 + m*16 + g*4 + r;
        atomicMin(&amin[(size_t)(mBase + row)*NC_SZ + c], key);
      }
    }
}

// ===================== xcat (R15, unchanged) ==============================
__global__ __launch_bounds__(512, 2) void k_xcat2(
    const ushort* __restrict__ xB, const ushort* __restrict__ Wcat,
    const float* __restrict__ b_f, const float* __restrict__ b_x1,
    ushort* __restrict__ pre, ushort* __restrict__ h1)
{
  __shared__ ushort smem[40960];
  const int tid = threadIdx.x;
  const int lane = tid & 63;
  const int w = tid >> 6;
  const int wm = w >> 2, wn = w & 3;
  const int g = lane >> 4, c0 = lane & 15;
  const int bid = blockIdx.x;
  const int nBase = (bid >> 7) * 512;
  const int mBase = (bid & 127) * 128;

  const int arow = tid >> 2, aslot = tid & 3;
  const ushort* aSrc = xB + (size_t)(mBase + arow)*IN_SZ + ((aslot ^ SWZ(arow))*8);
  const ushort* bSrc[4];
  #pragma unroll
  for (int j = 0; j < 4; ++j) {
    int q = tid + j*512, br = q >> 2, bs = ((q & 3) ^ SWZ(br)) * 8;
    bSrc[j] = Wcat + (size_t)(nBase + br)*IN_SZ + bs;
  }

  f32x4 acc[4][8];
  #pragma unroll
  for (int m=0;m<4;++m)
    #pragma unroll
    for (int n=0;n<8;++n) acc[m][n] = (f32x4){0.f,0.f,0.f,0.f};

  auto issue = [&](int t) {
    int kt = t * 32;
    ushort* ab = smem + (t & 1)*20480;
    ushort* bb = ab + 4096;
    gload_lds16(aSrc + kt, ab + tid*8);
    #pragma unroll
    for (int j=0;j<4;++j) gload_lds16(bSrc[j] + kt, bb + (tid + j*512)*8);
  };
  issue(0);
  for (int t = 0; t < 16; ++t) {
    WAITV(0); BAR();
    if (t + 1 < 16) issue(t + 1);
    const ushort* ab = smem + (t & 1)*20480;
    const ushort* bb = ab + 4096;
    short8 af[4], bf2[8];
    #pragma unroll
    for (int m=0;m<4;++m) {
      int ar = wm*64 + m*16 + c0;
      af[m] = *(const short8*)(ab + ar*32 + ((g ^ SWZ(ar)) * 8));
    }
    #pragma unroll
    for (int n=0;n<8;++n) {
      int br = wn*128 + n*16 + c0;
      bf2[n] = *(const short8*)(bb + br*32 + ((g ^ SWZ(br)) * 8));
    }
    SP1();
    #pragma unroll
    for (int m=0;m<4;++m)
      #pragma unroll
      for (int n=0;n<8;++n)
        acc[m][n] = __builtin_amdgcn_mfma_f32_16x16x32_bf16(af[m], bf2[n], acc[m][n], 0, 0, 0);
    SP0();
  }

  const int side = nBase >> 10;
  ushort* Cout = side ? h1 : pre;
  const float* bias = side ? b_x1 : b_f;
  const int obase = nBase & 1023;
  #pragma unroll
  for (int m=0;m<4;++m)
    #pragma unroll
    for (int n=0;n<8;++n) {
      int col = obase + wn*128 + n*16 + c0;
      float bb = bias[col];
      #pragma unroll
      for (int r=0;r<4;++r) {
        int row = mBase + wm*64 + m*16 + g*4 + r;
        Cout[(size_t)row*CH_SZ + col] = f2bf(fmaxf(acc[m][n][r] + bb, 0.f));
      }
    }
}

// ======= k_dec2: emb GEMM (M=128, N=64, K=1024) + fused decoder MLP ======
// 512 threads, 8 waves = 4M x 2N (wave tile 32x32), BK=64, 2-buffer 48KB
// -> 3 blocks/CU, grid 128. Epilogue: semb fp32 [128][65] LDS overlay
// (+1 pad = conflict-free), then 4-group wave-parallel MLP.
__global__ __launch_bounds__(512, 2) void k_dec2(
    const ushort* __restrict__ H1, const ushort* __restrict__ Wx2b,
    const float* __restrict__ b_x2, const float* __restrict__ Wd1,
    const float* __restrict__ bd1, const float* __restrict__ Wd2,
    const float* __restrict__ bd2, float* __restrict__ dec)
{
  __shared__ ushort smem[24576];                 // 48 KB: 2 x (A 16KB + B 8KB)
  const int tid = threadIdx.x;
  const int lane = tid & 63;
  const int w = tid >> 6;
  const int wm = w >> 1, wn = w & 1;             // 4M x 2N waves
  const int g = lane >> 4, c0 = lane & 15;
  const int mBase = blockIdx.x * 128;

  // staging: A 128x64 = 1024 chunks (2/thread); B 64x64 = 512 chunks (1/thread)
  const int af0 = tid, af1 = tid + 512;
  const int ar0 = af0 >> 3, ar1 = af1 >> 3;
  const ushort* aSrc0 = H1 + (size_t)(mBase + ar0)*CH_SZ + (((af0 & 7) ^ (ar0 & 7)) * 8);
  const ushort* aSrc1 = H1 + (size_t)(mBase + ar1)*CH_SZ + (((af1 & 7) ^ (ar1 & 7)) * 8);
  const int brw = tid >> 3;
  const ushort* bSrcD = Wx2b + (size_t)brw*CH_SZ + (((tid & 7) ^ (brw & 7)) * 8);

  f32x4 acc[2][2];
  #pragma unroll
  for (int m=0;m<2;++m)
    #pragma unroll
    for (int n=0;n<2;++n) acc[m][n] = (f32x4){0.f,0.f,0.f,0.f};

  auto issue = [&](int t) {
    int kt = t * 64;
    ushort* ab = smem + (t & 1)*12288;
    ushort* bb = ab + 8192;
    gload_lds16(aSrc0 + kt, ab + af0*8);
    gload_lds16(aSrc1 + kt, ab + af1*8);
    gload_lds16(bSrcD + kt, bb + tid*8);
  };
  issue(0);
  for (int t = 0; t < 16; ++t) {
    WAITV(0); BAR();
    if (t + 1 < 16) issue(t + 1);
    const ushort* ab = smem + (t & 1)*12288;
    const ushort* bb = ab + 8192;
    #pragma unroll
    for (int ks = 0; ks < 2; ++ks) {
      short8 af[2], bf2[2];
      #pragma unroll
      for (int m=0;m<2;++m) {
        int ar = wm*32 + m*16 + c0;
        af[m] = *(const short8*)(ab + ar*64 + (((ks*4+g) ^ (ar & 7)) * 8));
      }
      #pragma unroll
      for (int n=0;n<2;++n) {
        int br = wn*32 + n*16 + c0;
        bf2[n] = *(const short8*)(bb + br*64 + (((ks*4+g) ^ (br & 7)) * 8));
      }
      SP1();
      #pragma unroll
      for (int m=0;m<2;++m)
        #pragma unroll
        for (int n=0;n<2;++n)
          acc[m][n] = __builtin_amdgcn_mfma_f32_16x16x32_bf16(af[m], bf2[n], acc[m][n], 0, 0, 0);
      SP0();
    }
  }
  BAR();                                         // all frag reads done; reuse LDS

  // epilogue: semb [128][65] fp32 overlay (+1 pad)
  float* semb = (float*)smem;
  float* pdec = semb + 128*65;                   // [128][4]
  #pragma unroll
  for (int m=0;m<2;++m)
    #pragma unroll
    for (int n=0;n<2;++n) {
      int col = wn*32 + n*16 + c0;
      float bb = (col < 63) ? b_x2[col] : 0.f;
      #pragma unroll
      for (int r=0;r<4;++r) {
        int row = wm*32 + m*16 + g*4 + r;
        semb[row*65 + col] = acc[m][n][r] + bb;
      }
    }
  BAR();
  // wave-parallel decoder MLP: 4 groups x 16 j's
  {
    int grp = tid >> 7;                          // 0..3
    int lrow = tid & 127;
    float o = 0.f;
    #pragma unroll
    for (int jj = 0; jj < 16; ++jj) {
      int j = grp*16 + jj;
      if (j < 63) {
        float s = bd1[j];
        #pragma unroll 7
        for (int i=0;i<63;++i) s += semb[lrow*65 + i]*Wd1[j*63+i];
        o += fmaxf(s, 0.f)*Wd2[j];
      }
    }
    pdec[lrow*4 + grp] = o;
  }
  BAR();
  if (tid < 128) {
    dec[mBase + tid] = bd2[0] + pdec[tid*4] + pdec[tid*4+1]
                               + pdec[tid*4+2] + pdec[tid*4+3];
  }
}

// unpack argmin winners -> counts + dacc
__global__ __launch_bounds__(256) void k_fin2(
    const unsigned long long* __restrict__ amin, const float* __restrict__ zzG,
    int* __restrict__ counts, float* __restrict__ dacc)
{
  int t = blockIdx.x*256 + threadIdx.x;
  unsigned long long key = amin[t];
  unsigned k = (unsigned)(key >> 32);
  int ne = (int)(key & 0xFFFFFFFFu);
  unsigned u = (k & 0x80000000u) ? (k ^ 0x80000000u) : ~k;
  float bv; { union {unsigned uu; float f;} cv; cv.uu = u; bv = cv.f; }
  int c = t & 7;
  atomicAdd(&counts[c*NE_SZ + ne], 1);
  float dm = bv + zzG[t];
  #pragma unroll
  for (int off=1; off<64; off<<=1) dm += __shfl_xor(dm, off);
  if ((threadIdx.x & 63) == 0) atomicAdd(dacc, dm);
}

__global__ __launch_bounds__(256) void k_final(const int* __restrict__ counts,
                                               const float* __restrict__ dacc,
                                               float* __restrict__ out) {
  double s = 0.0;
  for (int i = threadIdx.x; i < NC_SZ*NE_SZ; i += 256) {
    double p = (double)counts[i] / (double)B_SZ;
    s -= p * log(p + 1e-10);
  }
  #pragma unroll
  for (int off=1; off<64; off<<=1) s += __shfl_xor(s, off);
  __shared__ double wsum[4];
  if ((threadIdx.x&63) == 0) wsum[threadIdx.x>>6] = s;
  __syncthreads();
  if (threadIdx.x == 0) {
    double e = wsum[0]+wsum[1]+wsum[2]+wsum[3];
    out[B_SZ]   = (float)((double)dacc[0] / ((double)B_SZ * (double)D_SZ));
    out[B_SZ+1] = (float)exp(e);
  }
}

extern "C" void kernel_launch(void* const* d_in, const int* in_sizes, int n_in,
                              void* d_out, int out_size, void* d_ws, size_t ws_size,
                              hipStream_t stream) {
  (void)in_sizes; (void)n_in; (void)out_size; (void)ws_size;
  const float* x    = (const float*)d_in[0];
  const float* W_f  = (const float*)d_in[1];
  const float* b_f  = (const float*)d_in[2];
  const float* W_x1 = (const float*)d_in[3];
  const float* b_x1 = (const float*)d_in[4];
  const float* W_x2 = (const float*)d_in[5];
  const float* b_x2 = (const float*)d_in[6];
  const float* Wq   = (const float*)d_in[7];
  const float* bq   = (const float*)d_in[8];
  const float* Wd1  = (const float*)d_in[9];
  const float* bd1  = (const float*)d_in[10];
  const float* Wd2  = (const float*)d_in[11];
  const float* bd2  = (const float*)d_in[12];
  const float* embed= (const float*)d_in[13];
  float* out = (float*)d_out;

  char* ws = (char*)d_ws;
  size_t off = 0;
  auto alloc = [&](size_t bytes) {
    void* p = ws + off; off = (off + bytes + 255) & ~(size_t)255; return p;
  };
  ushort* xb    = (ushort*)alloc((size_t)B_SZ*IN_SZ*2);
  ushort* preb  = (ushort*)alloc((size_t)B_SZ*CH_SZ*2);
  ushort* h1b   = (ushort*)alloc((size_t)B_SZ*CH_SZ*2);
  ushort* wcat  = (ushort*)alloc((size_t)2*CH_SZ*IN_SZ*2);
  ushort* wqb   = (ushort*)alloc((size_t)ED_SZ*CH_SZ*2);
  ushort* wx2b  = (ushort*)alloc((size_t)64*CH_SZ*2);
  ushort* embTb = (ushort*)alloc((size_t)NC_SZ*NE_SZ*D_SZ*2);
  float*  esq   = (float*)alloc((size_t)NC_SZ*NE_SZ*4);
  float*  zzG   = (float*)alloc((size_t)B_SZ*NC_SZ*4);
  unsigned long long* amin = (unsigned long long*)alloc((size_t)B_SZ*NC_SZ*8);
  int*    counts= (int*)alloc(4096*4);
  float*  dacc  = (float*)alloc(256);

  k_prep<<<(int)((P_TOTAL + 255)/256), 256, 0, stream>>>(
      x, W_f, W_x1, Wq, W_x2,
      xb, wcat, wqb, wx2b, esq, amin, counts, dacc);
  k_embT<<<dim3(NC_SZ, D_SZ/32, NE_SZ/32), dim3(32,8), 0, stream>>>(embed, embTb, esq);

  k_xcat2<<<(B_SZ/128)*4, 512, 0, stream>>>(xb, wcat, b_f, b_x1, preb, h1b);
  k_zdist<<<(B_SZ/128)*NC_SZ, 512, 0, stream>>>(
      preb, wqb, bq, embTb, esq, zzG, amin);
  k_dec2<<<B_SZ/128, 512, 0, stream>>>(h1b, wx2b, b_x2, Wd1, bd1, Wd2, bd2, out);
  k_fin2<<<(B_SZ*NC_SZ)/256, 256, 0, stream>>>(amin, zzG, counts, dacc);
  k_final<<<1, 256, 0, stream>>>(counts, dacc, out);
}

// Round 17
// 508.962 us; speedup vs baseline: 1.0072x; 1.0072x over previous
//
#include <hip/hip_runtime.h>
#include <hip/hip_bf16.h>
#include <math.h>

#define B_SZ   16384
#define IN_SZ  512
#define CH_SZ  1024
#define ED_SZ  4096
#define NC_SZ  8
#define NE_SZ  512
#define D_SZ   512

typedef short short8 __attribute__((ext_vector_type(8)));
typedef float f32x4 __attribute__((ext_vector_type(4)));

#define SWZ(r) ((((r)&3)^(((r)>>2)&3)))

__device__ __forceinline__ ushort f2bf(float f) {
  union { float f; unsigned u; } v; v.f = f;
  unsigned u = v.u;
  return (ushort)((u + 0x7fffu + ((u >> 16) & 1u)) >> 16);  // RNE
}
__device__ __forceinline__ float bf2f(ushort h) {
  union { unsigned u; float f; } v; v.u = ((unsigned)h) << 16; return v.f;
}

__device__ __forceinline__ void gload_lds16(const void* g, void* l) {
  __builtin_amdgcn_global_load_lds(
      (const __attribute__((address_space(1))) void*)g,
      (__attribute__((address_space(3))) void*)l, 16, 0, 0);
}

#define WAITV(N) asm volatile("s_waitcnt vmcnt(" #N ")" ::: "memory")
#define WAITL()  asm volatile("s_waitcnt lgkmcnt(0)" ::: "memory")
#define BAR()    asm volatile("s_barrier" ::: "memory")
#define SP1()    __builtin_amdgcn_s_setprio(1)
#define SP0()    __builtin_amdgcn_s_setprio(0)

// ========== k_prep: coalesced converts + inits (unchanged) ================
#define P_S0 2097152L
#define P_S1 131072L
#define P_S2 131072L
#define P_S3 1048576L
#define P_S4 16384L
#define P_S5 4096L
#define P_S6 131072L
#define P_S7 4097L
#define P_TOTAL (P_S0+P_S1+P_S2+P_S3+P_S4+P_S5+P_S6+P_S7)

__device__ __forceinline__ void cvt4(const float* __restrict__ s,
                                     ushort* __restrict__ d, long i4) {
  float4 v = ((const float4*)s)[i4];
  ushort4 o; o.x=f2bf(v.x); o.y=f2bf(v.y); o.z=f2bf(v.z); o.w=f2bf(v.w);
  ((ushort4*)d)[i4] = o;
}

__global__ __launch_bounds__(256) void k_prep(
    const float* __restrict__ x, const float* __restrict__ W_f,
    const float* __restrict__ W_x1, const float* __restrict__ Wq,
    const float* __restrict__ W_x2,
    ushort* __restrict__ xb, ushort* __restrict__ wcat,
    ushort* __restrict__ wqb, ushort* __restrict__ wx2b,
    float* __restrict__ esq, unsigned long long* __restrict__ amin,
    int* __restrict__ counts, float* __restrict__ dacc)
{
  long id = (long)blockIdx.x*256 + threadIdx.x;
  if (id < P_S0) { cvt4(x, xb, id); return; }            id -= P_S0;
  if (id < P_S1) { cvt4(W_f, wcat, id); return; }        id -= P_S1;
  if (id < P_S2) { cvt4(W_x1, wcat + (size_t)CH_SZ*IN_SZ, id); return; } id -= P_S2;
  if (id < P_S3) { cvt4(Wq, wqb, id); return; }          id -= P_S3;
  if (id < P_S4) {                                        // wx2 pad [64][1024]
    long i = id*4; int row = (int)(i >> 10), col = (int)(i & 1023);
    ushort4 o;
    if (row < 63) {
      float4 v = *(const float4*)(W_x2 + (size_t)row*1024 + col);
      o.x=f2bf(v.x); o.y=f2bf(v.y); o.z=f2bf(v.z); o.w=f2bf(v.w);
    } else { o.x=o.y=o.z=o.w=0; }
    *(ushort4*)(wx2b + i) = o;
    return;
  }                                                       id -= P_S4;
  if (id < P_S5) { esq[id] = 0.f; return; }               id -= P_S5;
  if (id < P_S6) { amin[id] = ~0ull; return; }            id -= P_S6;
  if (id < 4096) { counts[id] = 0; return; }
  if (id == 4096) { dacc[0] = 0.f; }
}

// coalesced LDS-transpose embT + esq (proven)
__global__ void k_embT(const float* __restrict__ embed,
                       ushort* __restrict__ embT, float* __restrict__ e_sq) {
  __shared__ float t[32][33];
  int c = blockIdx.x, d0 = blockIdx.y*32, n0 = blockIdx.z*32;
  const float* src = embed + ((size_t)c*D_SZ + d0)*NE_SZ + n0;
  for (int dy = threadIdx.y; dy < 32; dy += 8)
    t[dy][threadIdx.x] = src[(size_t)dy*NE_SZ + threadIdx.x];
  __syncthreads();
  ushort* dst = embT + ((size_t)c*NE_SZ + n0)*D_SZ + d0;
  for (int ny = threadIdx.y; ny < 32; ny += 8)
    dst[(size_t)ny*D_SZ + threadIdx.x] = f2bf(t[threadIdx.x][ny]);
  if (threadIdx.y == 0) {
    float s = 0.f;
    #pragma unroll
    for (int dd = 0; dd < 32; ++dd) { float v = t[dd][threadIdx.x]; s += v*v; }
    atomicAdd(&e_sq[c*NE_SZ + n0 + threadIdx.x], s);
  }
}

// ===================== fused z + dist kernel (unchanged) ==================
__global__ __launch_bounds__(512, 2) void k_zdist(
    const ushort* __restrict__ preB, const ushort* __restrict__ WqB,
    const float* __restrict__ bq, const ushort* __restrict__ embT,
    const float* __restrict__ esq, float* __restrict__ zzG,
    unsigned long long* __restrict__ amin)
{
  __shared__ ushort smem[81920];                 // 160 KB
  const int tid = threadIdx.x;
  const int lane = tid & 63;
  const int w = tid >> 6;
  const int wm = w >> 2, wn = w & 3;             // 2M x 4N waves
  const int g = lane >> 4, c0 = lane & 15;
  const int bid = blockIdx.x;
  const int c = bid >> 7;                        // codebook (XCD remap)
  const int mBase = (bid & 127) * 128;

  const int af0 = tid, af1 = tid + 512;
  const int ar0 = af0 >> 3, ar1 = af1 >> 3;
  const ushort* aSrc0 = preB + (size_t)(mBase + ar0)*CH_SZ + (((af0 & 7) ^ (ar0 & 7)) * 8);
  const ushort* aSrc1 = preB + (size_t)(mBase + ar1)*CH_SZ + (((af1 & 7) ^ (ar1 & 7)) * 8);
  const ushort* bSrcW[8];
  #pragma unroll
  for (int j = 0; j < 8; ++j) {
    int q = tid + j*512, br = q >> 3, bs = ((q & 7) ^ (br & 7)) * 8;
    bSrcW[j] = WqB + (size_t)(c*512 + br)*CH_SZ + bs;
  }

  f32x4 acc[4][8];
  #pragma unroll
  for (int m=0;m<4;++m)
    #pragma unroll
    for (int n=0;n<8;++n) acc[m][n] = (f32x4){0.f,0.f,0.f,0.f};

  {
    auto issue = [&](int t) {
      int kt = t * 64;
      ushort* ab = smem + (t & 1)*40960;
      ushort* bb = ab + 8192;
      gload_lds16(aSrc0 + kt, ab + af0*8);
      gload_lds16(aSrc1 + kt, ab + af1*8);
      #pragma unroll
      for (int j=0;j<8;++j) gload_lds16(bSrcW[j] + kt, bb + (tid + j*512)*8);
    };
    issue(0);
    for (int t = 0; t < 16; ++t) {
      WAITV(0); BAR();
      if (t + 1 < 16) issue(t + 1);
      const ushort* ab = smem + (t & 1)*40960;
      const ushort* bb = ab + 8192;
      #pragma unroll
      for (int ks = 0; ks < 2; ++ks) {
        short8 af[4], bf2[8];
        #pragma unroll
        for (int m=0;m<4;++m) {
          int ar = wm*64 + m*16 + c0;
          af[m] = *(const short8*)(ab + ar*64 + (((ks*4+g) ^ (ar & 7)) * 8));
        }
        #pragma unroll
        for (int n=0;n<8;++n) {
          int br = wn*128 + n*16 + c0;
          bf2[n] = *(const short8*)(bb + br*64 + (((ks*4+g) ^ (br & 7)) * 8));
        }
        SP1();
        #pragma unroll
        for (int m=0;m<4;++m)
          #pragma unroll
          for (int n=0;n<8;++n)
            acc[m][n] = __builtin_amdgcn_mfma_f32_16x16x32_bf16(af[m], bf2[n], acc[m][n], 0, 0, 0);
        SP0();
      }
    }
    BAR();
  }

  // phase 2: acc -> Z bf16 in LDS (swizzled) + row norms
  #pragma unroll
  for (int m=0;m<4;++m) {
    float sq[4] = {0.f,0.f,0.f,0.f};
    #pragma unroll
    for (int n=0;n<8;++n) {
      int col = wn*128 + n*16 + c0;
      float bb = bq[c*512 + col];
      #pragma unroll
      for (int r=0;r<4;++r) {
        int row = wm*64 + m*16 + g*4 + r;
        float v = acc[m][n][r] + bb;
        ushort hb = f2bf(v);
        int byte = row*1024 + ((col*2) ^ ((row&7)<<4));
        smem[byte>>1] = hb;
        float vb = bf2f(hb);
        sq[r] += vb*vb;
      }
    }
    #pragma unroll
    for (int r=0;r<4;++r) {
      float s = sq[r];
      s += __shfl_xor(s,1); s += __shfl_xor(s,2);
      s += __shfl_xor(s,4); s += __shfl_xor(s,8);
      if (c0 == 0) {
        int row = wm*64 + m*16 + g*4 + r;
        zzG[(size_t)(mBase + row)*NC_SZ + c] = s;
      }
    }
  }
  WAITL();
  BAR();

  // phase 3: dist GEMM from Z-LDS, staged embT ping-pong
  float rv[4][4]; int ri[4][4];
  #pragma unroll
  for (int m=0;m<4;++m)
    #pragma unroll
    for (int r=0;r<4;++r) { rv[m][r] = 3.0e38f; ri[m][r] = 0; }

  for (int h = 0; h < 2; ++h) {
    const ushort* eS0;
    const ushort* eS1;
    {
      int f0 = tid, f1 = tid + 512;
      int er0 = f0 >> 2, es0 = ((f0 & 3) ^ SWZ(er0)) * 8;
      int er1 = f1 >> 2, es1 = ((f1 & 3) ^ SWZ(er1)) * 8;
      eS0 = embT + (size_t)(c*512 + h*256 + er0)*512 + es0;
      eS1 = embT + (size_t)(c*512 + h*256 + er1)*512 + es1;
    }
    f32x4 acc2[4][4];
    #pragma unroll
    for (int m=0;m<4;++m)
      #pragma unroll
      for (int n=0;n<4;++n) acc2[m][n] = (f32x4){0.f,0.f,0.f,0.f};

    auto issue_e = [&](int s) {
      int kt = s * 32;
      ushort* eb = smem + 65536 + (s & 1)*8192;
      gload_lds16(eS0 + kt, eb + tid*8);
      gload_lds16(eS1 + kt, eb + (tid + 512)*8);
    };
    issue_e(0); issue_e(1);
    for (int s = 0; s < 16; ++s) {
      if (s < 15) { WAITV(2); } else { WAITV(0); }
      BAR();
      const ushort* eb = smem + 65536 + (s & 1)*8192;
      short8 af[4], bf2[4];
      #pragma unroll
      for (int m=0;m<4;++m) {
        int ar = wm*64 + m*16 + c0;
        af[m] = *(const short8*)(smem + ((ar*1024 + ((s*64 + g*16) ^ ((ar&7)<<4)))>>1));
      }
      #pragma unroll
      for (int n=0;n<4;++n) {
        int rbr = wn*64 + n*16 + c0;
        bf2[n] = *(const short8*)(eb + ((rbr*64 + ((g ^ SWZ(rbr))<<4))>>1));
      }
      SP1();
      #pragma unroll
      for (int m=0;m<4;++m)
        #pragma unroll
        for (int n=0;n<4;++n)
          acc2[m][n] = __builtin_amdgcn_mfma_f32_16x16x32_bf16(af[m], bf2[n], acc2[m][n], 0, 0, 0);
      SP0();
      BAR();
      if (s + 2 < 16) issue_e(s + 2);
    }
    #pragma unroll
    for (int m=0;m<4;++m)
      #pragma unroll
      for (int n=0;n<4;++n) {
        int ne = h*256 + wn*64 + n*16 + c0;
        float ev = esq[c*512 + ne];
        #pragma unroll
        for (int r=0;r<4;++r) {
          float v = ev - 2.0f*acc2[m][n][r];
          if (v < rv[m][r]) { rv[m][r] = v; ri[m][r] = ne; }
        }
      }
  }

  #pragma unroll
  for (int m=0;m<4;++m)
    #pragma unroll
    for (int r=0;r<4;++r) {
      float bv = rv[m][r]; int bi = ri[m][r];
      #pragma unroll
      for (int off=1; off<16; off<<=1) {
        float ov = __shfl_xor(bv, off);
        int   oi = __shfl_xor(bi, off);
        if (ov < bv || (ov == bv && oi < bi)) { bv = ov; bi = oi; }
      }
      if (c0 == 0) {
        unsigned u; { union {float f; unsigned uu;} cv; cv.f = bv; u = cv.uu; }
        unsigned k = (u & 0x80000000u) ? ~u : (u | 0x80000000u);
        unsigned long long key = (((unsigned long long)k) << 32) | (unsigned)bi;
        int row = wm*64 + m*16 + g*4 + r;
        atomicMin(&amin[(size_t)(mBase + row)*NC_SZ + c], key);
      }
    }
}

// ===================== xcat (unchanged) ===================================
__global__ __launch_bounds__(512, 2) void k_xcat2(
    const ushort* __restrict__ xB, const ushort* __restrict__ Wcat,
    const float* __restrict__ b_f, const float* __restrict__ b_x1,
    ushort* __restrict__ pre, ushort* __restrict__ h1)
{
  __shared__ ushort smem[40960];
  const int tid = threadIdx.x;
  const int lane = tid & 63;
  const int w = tid >> 6;
  const int wm = w >> 2, wn = w & 3;
  const int g = lane >> 4, c0 = lane & 15;
  const int bid = blockIdx.x;
  const int nBase = (bid >> 7) * 512;
  const int mBase = (bid & 127) * 128;

  const int arow = tid >> 2, aslot = tid & 3;
  const ushort* aSrc = xB + (size_t)(mBase + arow)*IN_SZ + ((aslot ^ SWZ(arow))*8);
  const ushort* bSrc[4];
  #pragma unroll
  for (int j = 0; j < 4; ++j) {
    int q = tid + j*512, br = q >> 2, bs = ((q & 3) ^ SWZ(br)) * 8;
    bSrc[j] = Wcat + (size_t)(nBase + br)*IN_SZ + bs;
  }

  f32x4 acc[4][8];
  #pragma unroll
  for (int m=0;m<4;++m)
    #pragma unroll
    for (int n=0;n<8;++n) acc[m][n] = (f32x4){0.f,0.f,0.f,0.f};

  auto issue = [&](int t) {
    int kt = t * 32;
    ushort* ab = smem + (t & 1)*20480;
    ushort* bb = ab + 4096;
    gload_lds16(aSrc + kt, ab + tid*8);
    #pragma unroll
    for (int j=0;j<4;++j) gload_lds16(bSrc[j] + kt, bb + (tid + j*512)*8);
  };
  issue(0);
  for (int t = 0; t < 16; ++t) {
    WAITV(0); BAR();
    if (t + 1 < 16) issue(t + 1);
    const ushort* ab = smem + (t & 1)*20480;
    const ushort* bb = ab + 4096;
    short8 af[4], bf2[8];
    #pragma unroll
    for (int m=0;m<4;++m) {
      int ar = wm*64 + m*16 + c0;
      af[m] = *(const short8*)(ab + ar*32 + ((g ^ SWZ(ar)) * 8));
    }
    #pragma unroll
    for (int n=0;n<8;++n) {
      int br = wn*128 + n*16 + c0;
      bf2[n] = *(const short8*)(bb + br*32 + ((g ^ SWZ(br)) * 8));
    }
    SP1();
    #pragma unroll
    for (int m=0;m<4;++m)
      #pragma unroll
      for (int n=0;n<8;++n)
        acc[m][n] = __builtin_amdgcn_mfma_f32_16x16x32_bf16(af[m], bf2[n], acc[m][n], 0, 0, 0);
    SP0();
  }

  const int side = nBase >> 10;
  ushort* Cout = side ? h1 : pre;
  const float* bias = side ? b_x1 : b_f;
  const int obase = nBase & 1023;
  #pragma unroll
  for (int m=0;m<4;++m)
    #pragma unroll
    for (int n=0;n<8;++n) {
      int col = obase + wn*128 + n*16 + c0;
      float bb = bias[col];
      #pragma unroll
      for (int r=0;r<4;++r) {
        int row = mBase + wm*64 + m*16 + g*4 + r;
        Cout[(size_t)row*CH_SZ + col] = f2bf(fmaxf(acc[m][n][r] + bb, 0.f));
      }
    }
}

// ======= k_dec3: emb GEMM (M=64, N=64, K=1024) + fused MLP, grid 256 =====
// 256 threads, 4 waves 2Mx2N (wave tile 32x32), BK=64, 2-buffer 32KB LDS,
// launch_bounds(256,4) -> >=4 blocks/CU. Full chip busy (256 blocks).
__global__ __launch_bounds__(256, 4) void k_dec3(
    const ushort* __restrict__ H1, const ushort* __restrict__ Wx2b,
    const float* __restrict__ b_x2, const float* __restrict__ Wd1,
    const float* __restrict__ bd1, const float* __restrict__ Wd2,
    const float* __restrict__ bd2, float* __restrict__ dec)
{
  __shared__ ushort smem[16384];                 // 32 KB: 2 x (A 8KB + B 8KB)
  const int tid = threadIdx.x;
  const int lane = tid & 63;
  const int w = tid >> 6;
  const int wm = w >> 1, wn = w & 1;             // 2M x 2N waves
  const int g = lane >> 4, c0 = lane & 15;
  const int mBase = blockIdx.x * 64;

  // staging: A 64x64 = 512 chunks (2/thread); B 64x64 = 512 chunks (2/thread)
  const int af0 = tid, af1 = tid + 256;
  const int ar0 = af0 >> 3, ar1 = af1 >> 3;
  const ushort* aSrc0 = H1 + (size_t)(mBase + ar0)*CH_SZ + (((af0 & 7) ^ (ar0 & 7)) * 8);
  const ushort* aSrc1 = H1 + (size_t)(mBase + ar1)*CH_SZ + (((af1 & 7) ^ (ar1 & 7)) * 8);
  const ushort* bSrc0 = Wx2b + (size_t)ar0*CH_SZ + (((af0 & 7) ^ (ar0 & 7)) * 8);
  const ushort* bSrc1 = Wx2b + (size_t)ar1*CH_SZ + (((af1 & 7) ^ (ar1 & 7)) * 8);

  f32x4 acc[2][2];
  #pragma unroll
  for (int m=0;m<2;++m)
    #pragma unroll
    for (int n=0;n<2;++n) acc[m][n] = (f32x4){0.f,0.f,0.f,0.f};

  auto issue = [&](int t) {
    int kt = t * 64;
    ushort* ab = smem + (t & 1)*8192;            // halves: [buf][A|B]
    ushort* bb = ab + 4096;
    gload_lds16(aSrc0 + kt, ab + af0*8);
    gload_lds16(aSrc1 + kt, ab + af1*8);
    gload_lds16(bSrc0 + kt, bb + af0*8);
    gload_lds16(bSrc1 + kt, bb + af1*8);
  };
  issue(0);
  for (int t = 0; t < 16; ++t) {
    WAITV(0); BAR();
    if (t + 1 < 16) issue(t + 1);
    const ushort* ab = smem + (t & 1)*8192;
    const ushort* bb = ab + 4096;
    #pragma unroll
    for (int ks = 0; ks < 2; ++ks) {
      short8 af[2], bf2[2];
      #pragma unroll
      for (int m=0;m<2;++m) {
        int ar = wm*32 + m*16 + c0;
        af[m] = *(const short8*)(ab + ar*64 + (((ks*4+g) ^ (ar & 7)) * 8));
      }
      #pragma unroll
      for (int n=0;n<2;++n) {
        int br = wn*32 + n*16 + c0;
        bf2[n] = *(const short8*)(bb + br*64 + (((ks*4+g) ^ (br & 7)) * 8));
      }
      SP1();
      #pragma unroll
      for (int m=0;m<2;++m)
        #pragma unroll
        for (int n=0;n<2;++n)
          acc[m][n] = __builtin_amdgcn_mfma_f32_16x16x32_bf16(af[m], bf2[n], acc[m][n], 0, 0, 0);
      SP0();
    }
  }
  BAR();                                         // all frag reads done; reuse LDS

  // epilogue: semb [64][65] fp32 overlay (+1 pad) + pdec [64][4]
  float* semb = (float*)smem;
  float* pdec = semb + 64*65;
  #pragma unroll
  for (int m=0;m<2;++m)
    #pragma unroll
    for (int n=0;n<2;++n) {
      int col = wn*32 + n*16 + c0;
      float bb = (col < 63) ? b_x2[col] : 0.f;
      #pragma unroll
      for (int r=0;r<4;++r) {
        int row = wm*32 + m*16 + g*4 + r;
        semb[row*65 + col] = acc[m][n][r] + bb;
      }
    }
  BAR();
  // wave-parallel decoder MLP: 4 groups (waves) x 16 j's
  {
    int grp = tid >> 6;                          // 0..3
    int lrow = tid & 63;
    float o = 0.f;
    #pragma unroll
    for (int jj = 0; jj < 16; ++jj) {
      int j = grp*16 + jj;
      if (j < 63) {
        float s = bd1[j];
        #pragma unroll 7
        for (int i=0;i<63;++i) s += semb[lrow*65 + i]*Wd1[j*63+i];
        o += fmaxf(s, 0.f)*Wd2[j];
      }
    }
    pdec[lrow*4 + grp] = o;
  }
  BAR();
  if (tid < 64) {
    dec[mBase + tid] = bd2[0] + pdec[tid*4] + pdec[tid*4+1]
                               + pdec[tid*4+2] + pdec[tid*4+3];
  }
}

// unpack argmin winners -> counts + dacc
__global__ __launch_bounds__(256) void k_fin2(
    const unsigned long long* __restrict__ amin, const float* __restrict__ zzG,
    int* __restrict__ counts, float* __restrict__ dacc)
{
  int t = blockIdx.x*256 + threadIdx.x;
  unsigned long long key = amin[t];
  unsigned k = (unsigned)(key >> 32);
  int ne = (int)(key & 0xFFFFFFFFu);
  unsigned u = (k & 0x80000000u) ? (k ^ 0x80000000u) : ~k;
  float bv; { union {unsigned uu; float f;} cv; cv.uu = u; bv = cv.f; }
  int c = t & 7;
  atomicAdd(&counts[c*NE_SZ + ne], 1);
  float dm = bv + zzG[t];
  #pragma unroll
  for (int off=1; off<64; off<<=1) dm += __shfl_xor(dm, off);
  if ((threadIdx.x & 63) == 0) atomicAdd(dacc, dm);
}

__global__ __launch_bounds__(256) void k_final(const int* __restrict__ counts,
                                               const float* __restrict__ dacc,
                                               float* __restrict__ out) {
  double s = 0.0;
  for (int i = threadIdx.x; i < NC_SZ*NE_SZ; i += 256) {
    double p = (double)counts[i] / (double)B_SZ;
    s -= p * log(p + 1e-10);
  }
  #pragma unroll
  for (int off=1; off<64; off<<=1) s += __shfl_xor(s, off);
  __shared__ double wsum[4];
  if ((threadIdx.x&63) == 0) wsum[threadIdx.x>>6] = s;
  __syncthreads();
  if (threadIdx.x == 0) {
    double e = wsum[0]+wsum[1]+wsum[2]+wsum[3];
    out[B_SZ]   = (float)((double)dacc[0] / ((double)B_SZ * (double)D_SZ));
    out[B_SZ+1] = (float)exp(e);
  }
}

extern "C" void kernel_launch(void* const* d_in, const int* in_sizes, int n_in,
                              void* d_out, int out_size, void* d_ws, size_t ws_size,
                              hipStream_t stream) {
  (void)in_sizes; (void)n_in; (void)out_size; (void)ws_size;
  const float* x    = (const float*)d_in[0];
  const float* W_f  = (const float*)d_in[1];
  const float* b_f  = (const float*)d_in[2];
  const float* W_x1 = (const float*)d_in[3];
  const float* b_x1 = (const float*)d_in[4];
  const float* W_x2 = (const float*)d_in[5];
  const float* b_x2 = (const float*)d_in[6];
  const float* Wq   = (const float*)d_in[7];
  const float* bq   = (const float*)d_in[8];
  const float* Wd1  = (const float*)d_in[9];
  const float* bd1  = (const float*)d_in[10];
  const float* Wd2  = (const float*)d_in[11];
  const float* bd2  = (const float*)d_in[12];
  const float* embed= (const float*)d_in[13];
  float* out = (float*)d_out;

  char* ws = (char*)d_ws;
  size_t off = 0;
  auto alloc = [&](size_t bytes) {
    void* p = ws + off; off = (off + bytes + 255) & ~(size_t)255; return p;
  };
  ushort* xb    = (ushort*)alloc((size_t)B_SZ*IN_SZ*2);
  ushort* preb  = (ushort*)alloc((size_t)B_SZ*CH_SZ*2);
  ushort* h1b   = (ushort*)alloc((size_t)B_SZ*CH_SZ*2);
  ushort* wcat  = (ushort*)alloc((size_t)2*CH_SZ*IN_SZ*2);
  ushort* wqb   = (ushort*)alloc((size_t)ED_SZ*CH_SZ*2);
  ushort* wx2b  = (ushort*)alloc((size_t)64*CH_SZ*2);
  ushort* embTb = (ushort*)alloc((size_t)NC_SZ*NE_SZ*D_SZ*2);
  float*  esq   = (float*)alloc((size_t)NC_SZ*NE_SZ*4);
  float*  zzG   = (float*)alloc((size_t)B_SZ*NC_SZ*4);
  unsigned long long* amin = (unsigned long long*)alloc((size_t)B_SZ*NC_SZ*8);
  int*    counts= (int*)alloc(4096*4);
  float*  dacc  = (float*)alloc(256);

  k_prep<<<(int)((P_TOTAL + 255)/256), 256, 0, stream>>>(
      x, W_f, W_x1, Wq, W_x2,
      xb, wcat, wqb, wx2b, esq, amin, counts, dacc);
  k_embT<<<dim3(NC_SZ, D_SZ/32, NE_SZ/32), dim3(32,8), 0, stream>>>(embed, embTb, esq);

  k_xcat2<<<(B_SZ/128)*4, 512, 0, stream>>>(xb, wcat, b_f, b_x1, preb, h1b);
  k_zdist<<<(B_SZ/128)*NC_SZ, 512, 0, stream>>>(
      preb, wqb, bq, embTb, esq, zzG, amin);
  k_dec3<<<B_SZ/64, 256, 0, stream>>>(h1b, wx2b, b_x2, Wd1, bd1, Wd2, bd2, out);
  k_fin2<<<(B_SZ*NC_SZ)/256, 256, 0, stream>>>(amin, zzG, counts, dacc);
  k_final<<<1, 256, 0, stream>>>(counts, dacc, out);
}